// Round 1
// baseline (2114.754 us; speedup 1.0000x reference)
//
#include <hip/hip_runtime.h>
#include <math.h>

#define DI __device__ __forceinline__

DI float sigm(float x){ return 1.0f/(1.0f+__expf(-x)); }
DI float tanhx(float x){ float ax=fabsf(x); float e=__expf(2.0f*ax); float t=1.0f-2.0f/(e+1.0f); return copysignf(t,x); }

// output layout (floats): log_y(4096*1024), a, a_mean, a_logvar (4096*8 each), mu(4096*4), Sigma(4096*16)
static constexpr size_t OFF_A   = 4194304;
static constexpr size_t OFF_AM  = OFF_A   + 32768;
static constexpr size_t OFF_ALV = OFF_AM  + 32768;
static constexpr size_t OFF_MU  = OFF_ALV + 32768;
static constexpr size_t OFF_SG  = OFF_MU  + 16384;

// ===================== Encoder: per-image fused conv0/1/2 + heads =====================
struct EncSh {
  float img[1024];
  float h0[7204];   // [co][15*15]
  float h1[1568];   // [co][49]
  float feat[288];
  float w[9216];
};

__global__ __launch_bounds__(256,2) void k_enc(
    const float* __restrict__ x, const float* __restrict__ eps,
    const float* __restrict__ Wc0, const float* __restrict__ bc0,
    const float* __restrict__ Wc1, const float* __restrict__ bc1,
    const float* __restrict__ Wc2, const float* __restrict__ bc2,
    const float* __restrict__ Wm, const float* __restrict__ bm,
    const float* __restrict__ Wlv, const float* __restrict__ blv,
    float* __restrict__ out)
{
  __shared__ EncSh E;
  const int n = blockIdx.x, tid = threadIdx.x;

  for (int i=tid;i<1024;i+=256) E.img[i]=x[(size_t)n*1024+i];
  for (int i=tid;i<9216;i+=256) E.w[i]=Wc1[i];
  __syncthreads();

  // conv0: 1->32ch, 32x32 -> 15x15, stride2, relu
  for (int i=tid;i<7200;i+=256){
    int co=i/225, p=i%225, oy=p/15, ox=p%15;
    float acc=bc0[co];
    const float* wp=Wc0+co*9;
    int base=2*oy*32+2*ox;
    #pragma unroll
    for(int ky=0;ky<3;ky++)
      #pragma unroll
      for(int kx=0;kx<3;kx++)
        acc += E.img[base+ky*32+kx]*wp[ky*3+kx];
    E.h0[i]=fmaxf(acc,0.0f);
  }
  __syncthreads();

  // conv1: 32->32, 15x15 -> 7x7, stride2, relu. thread = (co, 7 positions)
  {
    const int co=tid>>3, pg=tid&7;
    float acc[7]; int pb[7];
    #pragma unroll
    for(int q=0;q<7;q++){
      int p=pg+8*q; if(p>48)p=48;
      pb[q]=(2*(p/7))*15 + 2*(p%7);
      acc[q]=bc1[co];
    }
    for(int ci=0;ci<32;ci++){
      const float* hb=&E.h0[ci*225];
      const float* wb=&E.w[co*288+ci*9];
      #pragma unroll
      for(int ky=0;ky<3;ky++)
        #pragma unroll
        for(int kx=0;kx<3;kx++){
          float wv=wb[ky*3+kx];
          int off=ky*15+kx;
          #pragma unroll
          for(int q=0;q<7;q++) acc[q]+=wv*hb[pb[q]+off];
        }
    }
    #pragma unroll
    for(int q=0;q<7;q++){ int p=pg+8*q; if(p<49) E.h1[co*49+p]=fmaxf(acc[q],0.0f); }
  }
  __syncthreads();
  for (int i=tid;i<9216;i+=256) E.w[i]=Wc2[i];
  __syncthreads();

  // conv2: 32->32, 7x7 -> 3x3, stride2, relu
  for (int i=tid;i<288;i+=256){
    int co=i/9, p=i%9, oy=p/3, ox=p%3;
    float acc=bc2[co];
    for(int ci=0;ci<32;ci++){
      const float* hb=&E.h1[ci*49+2*oy*7+2*ox];
      const float* wb=&E.w[co*288+ci*9];
      #pragma unroll
      for(int ky=0;ky<3;ky++)
        #pragma unroll
        for(int kx=0;kx<3;kx++)
          acc += hb[ky*7+kx]*wb[ky*3+kx];
    }
    E.feat[i]=fmaxf(acc,0.0f);
  }
  __syncthreads();

  // heads: a_mean / a_logvar / a  (wave 0; lane = j*8+kk, partial K=36 each)
  if (tid<64){
    const int j=tid>>3, kk=tid&7;
    float s1=0.f,s2=0.f;
    const float* wm=Wm+j*288;
    const float* wl=Wlv+j*288;
    #pragma unroll 6
    for(int m=kk*36;m<kk*36+36;m++){ float f=E.feat[m]; s1+=f*wm[m]; s2+=f*wl[m]; }
    #pragma unroll
    for(int d=4;d>0;d>>=1){ s1+=__shfl_down(s1,d,64); s2+=__shfl_down(s2,d,64); }
    if(kk==0){
      size_t o=(size_t)n*8+j;
      float am=s1+bm[j];
      float lv=sigm(s2+blv[j]);
      float av=am+eps[o]*__expf(0.5f*lv);
      out[OFF_AM+o]=am;
      out[OFF_ALV+o]=lv;
      out[OFF_A+o]=av;
    }
  }
}

// ===================== Main kernel: 32 seq blocks (LSTM+KF+RTS) + 4096 decoder blocks =====================
struct DecSh {
  float aa[8];
  float d0[288];
  float t0[1664];   // [ci][52] (49 used)
  float t1[7200];   // [co][225]
  float w[9216];    // staged transposed weights
};
struct SeqSh {
  float a_loc[1024];   // a[s][j] for this batch
  float a0[8];
  float h[52];
  float gates[200];
  float wa[152];
  float logit[4];
  float alpha[384];    // [s][k]
  float muf[512];      // [s][4]
  float Sigf[2048];    // [s][16]
  float Sigp[2048];    // [s][16]
};
union MainSh { DecSh d; SeqSh q; };

__global__ __launch_bounds__(512,4) void k_main(
    const float* __restrict__ Wd, const float* __restrict__ bd,
    const float* __restrict__ Wt0, const float* __restrict__ bt0,
    const float* __restrict__ Wt1, const float* __restrict__ bt1,
    const float* __restrict__ Wt2, const float* __restrict__ bt2,
    const float* __restrict__ Wg, const float* __restrict__ bgp,
    const float* __restrict__ Ag, const float* __restrict__ Bg, const float* __restrict__ Cg,
    const float* __restrict__ a_init,
    const float* __restrict__ W_ih, const float* __restrict__ W_hh,
    const float* __restrict__ b_ih, const float* __restrict__ b_hh,
    const float* __restrict__ Wa, const float* __restrict__ ba,
    float* __restrict__ out)
{
  __shared__ MainSh sh;
  const int tid=threadIdx.x;
  const float* aglob = out + OFF_A;

  if (blockIdx.x < 32){
    // ================= sequential path (one batch per block) =================
    SeqSh& Q = sh.q;
    const int b=blockIdx.x;
    for (int i=tid;i<1024;i+=512){ int s=i>>3, j=i&7; Q.a_loc[i]=aglob[((size_t)s*32+b)*8+j]; }
    if (tid<8)   Q.a0[tid]=a_init[tid];
    if (tid<150) Q.wa[tid]=Wa[tid];
    if (tid<50)  Q.h[tid]=0.f;
    float wr[50], wi[8], bsum=0.f, creg=0.f;
    if (tid<200){
      #pragma unroll
      for(int k=0;k<50;k++) wr[k]=W_hh[tid*50+k];
      #pragma unroll
      for(int j=0;j<8;j++) wi[j]=W_ih[tid*8+j];
      bsum=b_ih[tid]+b_hh[tid];
    }
    __syncthreads();
    // ---- LSTM over S=128 (2 barriers/step; logits/alpha pipelined one step behind) ----
    for (int s=0;s<128;s++){
      if (tid<200){
        float aA=bsum, aB=0.f;
        const float* ap = (s==0) ? Q.a0 : (Q.a_loc + (s-1)*8);
        #pragma unroll
        for(int j=0;j<8;j++) aA+=ap[j]*wi[j];
        #pragma unroll
        for(int k=0;k<50;k+=2){ aA+=Q.h[k]*wr[k]; aB+=Q.h[k+1]*wr[k+1]; }
        Q.gates[tid]=aA+aB;
      } else if (tid>=208 && tid<211){
        if (s>0){
          int j=tid-208;
          float lv=ba[j];
          const float* wap=&Q.wa[j*50];
          #pragma unroll 5
          for(int k=0;k<50;k++) lv+=Q.h[k]*wap[k];
          Q.logit[j]=lv;
        }
      }
      __syncthreads();
      if (tid<50){
        float ig=sigm(Q.gates[tid]);
        float fg=sigm(Q.gates[50+tid]);
        float gg=tanhx(Q.gates[100+tid]);
        float og=sigm(Q.gates[150+tid]);
        creg=fg*creg+ig*gg;
        Q.h[tid]=og*tanhx(creg);
      } else if (tid>=64 && tid<67 && s>0){
        int j=tid-64;
        float l0=Q.logit[0], l1=Q.logit[1], l2=Q.logit[2];
        float mx=fmaxf(l0,fmaxf(l1,l2));
        float e0=__expf(l0-mx), e1=__expf(l1-mx), e2=__expf(l2-mx);
        float lj=(j==0)?l0:((j==1)?l1:l2);
        Q.alpha[(s-1)*3+j]=__expf(lj-mx)/(e0+e1+e2);
      }
      __syncthreads();
    }
    if (tid<3){
      float lv=ba[tid];
      const float* wap=&Q.wa[tid*50];
      #pragma unroll 5
      for(int k=0;k<50;k++) lv+=Q.h[k]*wap[k];
      Q.logit[tid]=lv;
    }
    __syncthreads();
    if (tid<3){
      float l0=Q.logit[0], l1=Q.logit[1], l2=Q.logit[2];
      float mx=fmaxf(l0,fmaxf(l1,l2));
      float e0=__expf(l0-mx), e1=__expf(l1-mx), e2=__expf(l2-mx);
      float lj=(tid==0)?l0:((tid==1)?l1:l2);
      Q.alpha[127*3+tid]=__expf(lj-mx)/(e0+e1+e2);
    }
    __syncthreads();
    if (tid>=64) return;

    // ---- Kalman filter: one wave, matrices one-element-per-lane (r=tid>>3, c=tid&7) ----
    const int r=tid>>3, c=tid&7;
    float A0=0,A1=0,A2=0,B0=0,B1=0,B2=0,C0=0,C1=0,C2=0;
    if (r<4&&c<4){ A0=Ag[r*4+c]; A1=Ag[16+r*4+c]; A2=Ag[32+r*4+c]; }
    if (r<4){ B0=Bg[r*8+c]; B1=Bg[32+r*8+c]; B2=Bg[64+r*8+c]; }
    if (c<4){ C0=Cg[r*4+c]; C1=Cg[32+r*4+c]; C2=Cg[64+r*4+c]; }
    float mu0=0,mu1=0,mu2=0,mu3=0, Sg=0.f;
    for (int s=0;s<128;s++){
      float al0=Q.alpha[s*3+0], al1=Q.alpha[s*3+1], al2=Q.alpha[s*3+2];
      float At=al0*A0+al1*A1+al2*A2;
      float Bt=al0*B0+al1*B1+al2*B2;
      float Ct=al0*C0+al1*C1+al2*C2;
      // mu_p = A mu + B u
      float mp0,mp1,mp2,mp3;
      {
        float mcc=(c==0)?mu0:((c==1)?mu1:((c==2)?mu2:((c==3)?mu3:0.f)));
        float vA=At*mcc;
        vA+=__shfl_xor(vA,1,64); vA+=__shfl_xor(vA,2,64);
        float uc;
        if (s==0) uc=Q.a0[c]; else uc=Q.a_loc[(s-1)*8+c];
        float vB=Bt*uc;
        vB+=__shfl_xor(vB,1,64); vB+=__shfl_xor(vB,2,64); vB+=__shfl_xor(vB,4,64);
        float comb=vA+vB;
        mp0=__shfl(comb,0,64); mp1=__shfl(comb,8,64); mp2=__shfl(comb,16,64); mp3=__shfl(comb,24,64);
      }
      // Sig_p = A Sig A^T + Q
      float Sp;
      {
        float T=0.f;
        #pragma unroll
        for(int k=0;k<4;k++) T+=__shfl(At,(r<<3)|k,64)*__shfl(Sg,(k<<3)|c,64);
        float sp=0.f;
        #pragma unroll
        for(int k=0;k<4;k++) sp+=__shfl(T,(r<<3)|k,64)*__shfl(At,(c<<3)|k,64);
        Sp=sp+((r==c)?0.08f:0.f);
      }
      if (s==0){ mp0=0;mp1=0;mp2=0;mp3=0; Sp=(r==c)?20.f:0.f; }
      if (r<4&&c<4) Q.Sigp[s*16+r*4+c]=Sp;
      // res = a_t - C mu_p  (row sums held at column 0 of each row)
      float rr;
      {
        float mpc=(c==0)?mp0:((c==1)?mp1:((c==2)?mp2:((c==3)?mp3:0.f)));
        float v=Ct*mpc;
        v+=__shfl_xor(v,1,64); v+=__shfl_xor(v,2,64);
        rr=Q.a_loc[s*8+r]-v;
      }
      // CP = C Sig_p  (8x4)
      float CP=0.f;
      #pragma unroll
      for(int k=0;k<4;k++) CP+=__shfl(Ct,(r<<3)|k,64)*__shfl(Sp,(k<<3)|c,64);
      // S = CP C^T + R  (8x8)
      float Sm=0.f;
      #pragma unroll
      for(int k=0;k<4;k++) Sm+=__shfl(CP,(r<<3)|k,64)*__shfl(Ct,(c<<3)|k,64);
      Sm+=(r==c)?0.03f:0.f;
      // Gauss-Jordan invert S (SPD, no pivoting) entirely via shuffles
      float gA=Sm, gB=(r==c)?1.f:0.f;
      #pragma unroll
      for(int k=0;k<8;k++){
        float piv=__shfl(gA,(k<<3)|k,64);
        float pinv=1.f/piv;
        float sa=__shfl(gA,(k<<3)|c,64)*pinv;
        float sb=__shfl(gB,(k<<3)|c,64)*pinv;
        float fac=__shfl(gA,(r<<3)|k,64);
        bool dg=(r==k);
        gA=dg?sa:fmaf(-fac,sa,gA);
        gB=dg?sb:fmaf(-fac,sb,gB);
      }
      // Kt = Sig_p C^T Sinv = CP^T Sinv  (4x8, rows r<4)
      float Kt=0.f;
      #pragma unroll
      for(int k=0;k<8;k++) Kt+=__shfl(CP,(k<<3)|r,64)*__shfl(gB,(k<<3)|c,64);
      // mu_f = mu_p + Kt res
      float resc=__shfl(rr,c<<3,64);
      float vv=Kt*resc;
      vv+=__shfl_xor(vv,1,64); vv+=__shfl_xor(vv,2,64); vv+=__shfl_xor(vv,4,64);
      float mufr=((r==0)?mp0:((r==1)?mp1:((r==2)?mp2:mp3)))+vv;
      float nm0=__shfl(mufr,0,64), nm1=__shfl(mufr,8,64), nm2=__shfl(mufr,16,64), nm3=__shfl(mufr,24,64);
      if (r<4&&c==0) Q.muf[s*4+r]=mufr;
      // IKC = I - Kt C (4x4)
      float IK=(r==c)?1.f:0.f;
      #pragma unroll
      for(int m=0;m<8;m++) IK-=__shfl(Kt,(r<<3)|m,64)*__shfl(Ct,(m<<3)|c,64);
      // Sig_f = IKC Sig_p IKC^T + 0.03 Kt Kt^T
      float T2=0.f;
      #pragma unroll
      for(int k=0;k<4;k++) T2+=__shfl(IK,(r<<3)|k,64)*__shfl(Sp,(k<<3)|c,64);
      float Sf=0.f;
      #pragma unroll
      for(int k=0;k<4;k++) Sf+=__shfl(T2,(r<<3)|k,64)*__shfl(IK,(c<<3)|k,64);
      float kk2=0.f;
      #pragma unroll
      for(int m=0;m<8;m++) kk2+=__shfl(Kt,(r<<3)|m,64)*__shfl(Kt,(c<<3)|m,64);
      Sf+=0.03f*kk2;
      if (r<4&&c<4) Q.Sigf[s*16+r*4+c]=Sf;
      mu0=nm0; mu1=nm1; mu2=nm2; mu3=nm3; Sg=Sf;
    }
    // ---- RTS smoother (reverse) ----
    if (r<4&&c==0) out[OFF_MU+((size_t)127*32+b)*4+r]=Q.muf[127*4+r];
    if (r<4&&c<4)  out[OFF_SG+((size_t)127*32+b)*16+r*4+c]=Q.Sigf[127*16+r*4+c];
    float ms0=Q.muf[508], ms1=Q.muf[509], ms2=Q.muf[510], ms3=Q.muf[511];
    float Ss=(r<4&&c<4)?Q.Sigf[127*16+r*4+c]:0.f;
    for (int n2=126;n2>=0;n2--){
      float al0=Q.alpha[(n2+1)*3+0], al1=Q.alpha[(n2+1)*3+1], al2=Q.alpha[(n2+1)*3+2];
      float An=al0*A0+al1*A1+al2*A2;
      float Sfv=(r<4&&c<4)?Q.Sigf[n2*16+r*4+c]:0.f;
      float Spn=(r<4&&c<4)?Q.Sigp[(n2+1)*16+r*4+c]:0.f;
      // invert Sp_{n+1} (4x4 region)
      float gA=Spn, gB=(r==c)?1.f:0.f;
      #pragma unroll
      for(int k=0;k<4;k++){
        float piv=__shfl(gA,(k<<3)|k,64);
        float pinv=1.f/piv;
        float sa=__shfl(gA,(k<<3)|c,64)*pinv;
        float sb=__shfl(gB,(k<<3)|c,64)*pinv;
        float fac=__shfl(gA,(r<<3)|k,64);
        bool dg=(r==k);
        gA=dg?sa:fmaf(-fac,sa,gA);
        gB=dg?sb:fmaf(-fac,sb,gB);
      }
      // J = Sf A_n^T Spinv
      float T=0.f;
      #pragma unroll
      for(int k=0;k<4;k++) T+=__shfl(Sfv,(r<<3)|k,64)*__shfl(An,(c<<3)|k,64);
      float J=0.f;
      #pragma unroll
      for(int k=0;k<4;k++) J+=__shfl(T,(r<<3)|k,64)*__shfl(gB,(k<<3)|c,64);
      // mu_new = muf + J (mu_s - muf_{n+1})
      float dmc;
      {
        float msc=(c==0)?ms0:((c==1)?ms1:((c==2)?ms2:((c==3)?ms3:0.f)));
        float mfn=Q.muf[(n2+1)*4+((c<4)?c:0)];
        dmc=(c<4)?(msc-mfn):0.f;
      }
      float v=J*dmc;
      v+=__shfl_xor(v,1,64); v+=__shfl_xor(v,2,64);
      float munr=Q.muf[n2*4+((r<4)?r:0)]+v;
      // Sig_new = Sf + J (Sig_s - Sp_n) J^T
      float Dv=Ss-Spn;
      float T2=0.f;
      #pragma unroll
      for(int k=0;k<4;k++) T2+=__shfl(J,(r<<3)|k,64)*__shfl(Dv,(k<<3)|c,64);
      float Sn=Sfv;
      #pragma unroll
      for(int k=0;k<4;k++) Sn+=__shfl(T2,(r<<3)|k,64)*__shfl(J,(c<<3)|k,64);
      if (r<4&&c==0) out[OFF_MU+((size_t)n2*32+b)*4+r]=munr;
      if (r<4&&c<4)  out[OFF_SG+((size_t)n2*32+b)*16+r*4+c]=Sn;
      ms0=__shfl(munr,0,64); ms1=__shfl(munr,8,64); ms2=__shfl(munr,16,64); ms3=__shfl(munr,24,64);
      Ss=Sn;
    }
    return;
  }

  // ================= decoder path (one image per block) =================
  DecSh& D = sh.d;
  const int n = blockIdx.x - 32;
  if (tid<8) D.aa[tid]=aglob[(size_t)n*8+tid];
  __syncthreads();
  if (tid<288){
    float acc=bd[tid];
    #pragma unroll
    for(int j=0;j<8;j++) acc+=D.aa[j]*Wd[tid*8+j];
    D.d0[tid]=acc;
  }
  __syncthreads();
  // convT0 gather: 3x3 -> 7x7, relu
  for (int i=tid;i<1568;i+=512){
    int co=i/49, p=i%49, oh=p/7, ow=p%7;
    float acc=bt0[co];
    #pragma unroll
    for(int kh=0;kh<3;kh++){
      int iht=oh-kh;
      if (iht<0 || (iht&1) || iht>4) continue;
      int ih=iht>>1;
      #pragma unroll
      for(int kw=0;kw<3;kw++){
        int iwt=ow-kw;
        if (iwt<0 || (iwt&1) || iwt>4) continue;
        int iw=iwt>>1;
        const float* wp=Wt0+co*9+kh*3+kw;
        const float* dp=&D.d0[ih*3+iw];
        for(int ci=0;ci<32;ci++) acc+=dp[ci*9]*wp[ci*288];
      }
    }
    D.t0[co*52+p]=fmaxf(acc,0.0f);
  }
  __syncthreads();
  // stage Wt1 transposed [tap][co][ci]; init t1 = bias
  for (int i=tid;i<9216;i+=512){
    int ci=i/288, rm=i%288, co=rm/9, tap=rm%9;
    D.w[tap*1024+co*32+ci]=Wt1[i];
  }
  for (int i=tid;i<7200;i+=512) D.t1[i]=bt1[i/225];
  __syncthreads();
  // convT1 scatter: 7x7 -> 15x15 (9 taps, barrier between taps)
  {
    const int co=tid>>4, pt=tid&15, p0=4*pt;
    for (int tap=0;tap<9;tap++){
      const int kh=tap/3, kw=tap%3;
      float a0=0,a1=0,a2=0,a3=0;
      const float* wrow=&D.w[tap*1024+co*32];
      for (int ci=0;ci<32;ci+=4){
        float4 wv=*(const float4*)&wrow[ci];
        float4 tv0=*(const float4*)&D.t0[(ci+0)*52+p0];
        a0+=wv.x*tv0.x; a1+=wv.x*tv0.y; a2+=wv.x*tv0.z; a3+=wv.x*tv0.w;
        float4 tv1=*(const float4*)&D.t0[(ci+1)*52+p0];
        a0+=wv.y*tv1.x; a1+=wv.y*tv1.y; a2+=wv.y*tv1.z; a3+=wv.y*tv1.w;
        float4 tv2=*(const float4*)&D.t0[(ci+2)*52+p0];
        a0+=wv.z*tv2.x; a1+=wv.z*tv2.y; a2+=wv.z*tv2.z; a3+=wv.z*tv2.w;
        float4 tv3=*(const float4*)&D.t0[(ci+3)*52+p0];
        a0+=wv.w*tv3.x; a1+=wv.w*tv3.y; a2+=wv.w*tv3.z; a3+=wv.w*tv3.w;
      }
      #pragma unroll
      for(int q=0;q<4;q++){
        int p=p0+q;
        if (p<49){
          int ih=p/7, iw=p%7;
          float av=(q==0)?a0:((q==1)?a1:((q==2)?a2:a3));
          D.t1[co*225+(2*ih+kh)*15+(2*iw+kw)]+=av;
        }
      }
      __syncthreads();
    }
  }
  // relu(t1); stage Wt2 transposed [tap][ci][co]
  for (int i=tid;i<7200;i+=512) D.t1[i]=fmaxf(D.t1[i],0.0f);
  for (int i=tid;i<9216;i+=512){
    int ci=i/288, rm=i%288, co=rm/9, tap=rm%9;
    D.w[tap*1024+ci*32+co]=Wt2[i];
  }
  __syncthreads();
  // convT2 (15x15 -> 32x32, op=1) fused with relu + <Wg> reduction + sigmoid.
  // Parity-class gather: 4 classes x 2 waves, each thread owns 2 pixels x all 32 co.
  {
    const int cls=tid>>7, ph=cls>>1, pw=cls&1;
    const int l=tid&127, ii=l>>3, j0=l&7;
    float acc0[32], acc1[32];
    #pragma unroll
    for(int co=0;co<32;co++){ float bz=bt2[co]; acc0[co]=bz; acc1[co]=bz; }
    const int nth=ph?1:2, ntw=pw?1:2;
    for (int th=0;th<nth;th++){
      const int kh=ph?1:(2*th);
      const int ih=ii-th;
      const bool vh=(ih>=0)&&(ih<15);
      for (int tw=0;tw<ntw;tw++){
        const int kw=pw?1:(2*tw);
        const int iwA=j0-tw, iwB=j0+8-tw;
        const bool vA=vh&&(iwA>=0);
        const bool vB=vh&&(iwB<15);
        const int tap=kh*3+kw;
        const int bA=(vh?ih:0)*15+(vA?iwA:0);
        const int bB=(vh?ih:0)*15+(vB?iwB:0);
        const float* wt=&D.w[tap*1024];
        for (int ci=0;ci<32;ci++){
          float tA=D.t1[ci*225+bA]; if(!vA) tA=0.f;
          float tB=D.t1[ci*225+bB]; if(!vB) tB=0.f;
          const float* wci=wt+ci*32;
          #pragma unroll
          for (int c4=0;c4<32;c4+=4){
            float4 w4=*(const float4*)&wci[c4];
            acc0[c4+0]+=w4.x*tA; acc1[c4+0]+=w4.x*tB;
            acc0[c4+1]+=w4.y*tA; acc1[c4+1]+=w4.y*tB;
            acc0[c4+2]+=w4.z*tA; acc1[c4+2]+=w4.z*tB;
            acc0[c4+3]+=w4.w*tA; acc1[c4+3]+=w4.w*tB;
          }
        }
      }
    }
    float s0=bgp[0], s1=bgp[0];
    #pragma unroll
    for(int co=0;co<32;co++){ s0+=fmaxf(acc0[co],0.f)*Wg[co]; s1+=fmaxf(acc1[co],0.f)*Wg[co]; }
    const int oh=ph+2*ii;
    size_t ob=(size_t)n*1024+(size_t)oh*32;
    out[ob+pw+2*j0]=sigm(s0);
    out[ob+pw+2*(j0+8)]=sigm(s1);
  }
}

extern "C" void kernel_launch(void* const* d_in, const int* in_sizes, int n_in,
                              void* d_out, int out_size, void* d_ws, size_t ws_size,
                              hipStream_t stream)
{
  const float* x    =(const float*)d_in[0];
  const float* eps  =(const float*)d_in[1];
  const float* Wc0  =(const float*)d_in[2];
  const float* bc0  =(const float*)d_in[3];
  const float* Wc1  =(const float*)d_in[4];
  const float* bc1  =(const float*)d_in[5];
  const float* Wc2  =(const float*)d_in[6];
  const float* bc2  =(const float*)d_in[7];
  const float* Wm   =(const float*)d_in[8];
  const float* bm   =(const float*)d_in[9];
  const float* Wlv  =(const float*)d_in[10];
  const float* blv  =(const float*)d_in[11];
  const float* Wd   =(const float*)d_in[12];
  const float* bd   =(const float*)d_in[13];
  const float* Wt0  =(const float*)d_in[14];
  const float* bt0  =(const float*)d_in[15];
  const float* Wt1  =(const float*)d_in[16];
  const float* bt1  =(const float*)d_in[17];
  const float* Wt2  =(const float*)d_in[18];
  const float* bt2  =(const float*)d_in[19];
  const float* Wg   =(const float*)d_in[20];
  const float* bg   =(const float*)d_in[21];
  const float* A    =(const float*)d_in[22];
  const float* Bm   =(const float*)d_in[23];
  const float* Cm   =(const float*)d_in[24];
  const float* a0   =(const float*)d_in[25];
  const float* W_ih =(const float*)d_in[26];
  const float* W_hh =(const float*)d_in[27];
  const float* b_ih =(const float*)d_in[28];
  const float* b_hh =(const float*)d_in[29];
  const float* Wa   =(const float*)d_in[30];
  const float* ba   =(const float*)d_in[31];
  float* out=(float*)d_out;

  k_enc<<<4096,256,0,stream>>>(x,eps,Wc0,bc0,Wc1,bc1,Wc2,bc2,Wm,bm,Wlv,blv,out);
  // 32 sequential (batch) blocks dispatched first so they overlap with the 4096 decoder blocks
  k_main<<<4128,512,0,stream>>>(Wd,bd,Wt0,bt0,Wt1,bt1,Wt2,bt2,Wg,bg,A,Bm,Cm,a0,
                                W_ih,W_hh,b_ih,b_hh,Wa,ba,out);
}

// Round 2
// 1080.530 us; speedup vs baseline: 1.9571x; 1.9571x over previous
//
#include <hip/hip_runtime.h>
#include <math.h>

#define DI __device__ __forceinline__

DI float sigm(float x){ return 1.0f/(1.0f+__expf(-x)); }
DI float tanhx(float x){ float ax=fabsf(x); float e=__expf(2.0f*ax); float t=1.0f-2.0f/(e+1.0f); return copysignf(t,x); }

DI float bflo(unsigned u){ return __uint_as_float(u<<16); }
DI float bfhi(unsigned u){ return __uint_as_float(u&0xffff0000u); }
DI float bfs(unsigned short s){ return __uint_as_float(((unsigned)s)<<16); }
DI unsigned short f2bf(float x){ unsigned u=__float_as_uint(x); return (unsigned short)((u+0x7fffu+((u>>16)&1u))>>16); }

// output layout (floats): log_y(4096*1024), a, a_mean, a_logvar (4096*8 each), mu(4096*4), Sigma(4096*16)
static constexpr size_t OFF_A   = 4194304;
static constexpr size_t OFF_AM  = OFF_A   + 32768;
static constexpr size_t OFF_ALV = OFF_AM  + 32768;
static constexpr size_t OFF_MU  = OFF_ALV + 32768;
static constexpr size_t OFF_SG  = OFF_MU  + 16384;

// ===================== Encoder =====================
struct EncSh {
  float img[1024];
  float h0[7680];                         // [ci][15 rows][16 cols] padded
  float h1[1568];                         // [co][49]
  float feat[288];
  alignas(16) unsigned short wb[16648];   // [co][ci][16] bf16, co stride 520
};

__global__ __launch_bounds__(256,2) void k_enc(
    const float* __restrict__ x, const float* __restrict__ eps,
    const float* __restrict__ Wc0, const float* __restrict__ bc0,
    const float* __restrict__ Wc1, const float* __restrict__ bc1,
    const float* __restrict__ Wc2, const float* __restrict__ bc2,
    const float* __restrict__ Wm, const float* __restrict__ bm,
    const float* __restrict__ Wlv, const float* __restrict__ blv,
    float* __restrict__ out)
{
  __shared__ EncSh E;
  const int n = blockIdx.x, tid = threadIdx.x;

  for (int i=tid;i<1024;i+=256) E.img[i]=x[(size_t)n*1024+i];
  // stage Wc1 as bf16 [co][ci][16] (dst-major: conflict-free writes)
  for (int i=tid;i<16384;i+=256){
    int tap=i&15, ci=(i>>4)&31, co=i>>9;
    E.wb[co*520+ci*16+tap] = (tap<9) ? f2bf(Wc1[co*288+ci*9+tap]) : (unsigned short)0;
  }
  __syncthreads();

  // conv0: 1->32ch, 32x32 -> 15x15, stride2, relu
  for (int i=tid;i<7200;i+=256){
    int co=i/225, p=i%225, oy=p/15, ox=p%15;
    float acc=bc0[co];
    const float* wp=Wc0+co*9;
    int base=2*oy*32+2*ox;
    #pragma unroll
    for(int ky=0;ky<3;ky++)
      #pragma unroll
      for(int kx=0;kx<3;kx++)
        acc += E.img[base+ky*32+kx]*wp[ky*3+kx];
    E.h0[co*240+oy*16+ox]=fmaxf(acc,0.0f);
  }
  __syncthreads();

  // conv1: 32->32, 15x15 -> 7x7, stride2, relu. thread = (oy, co), full output row per thread
  if (tid<224){
    const int oy=tid>>5, co=tid&31;
    float acc[7];
    #pragma unroll
    for(int q=0;q<7;q++) acc[q]=bc1[co];
    const unsigned short* wrow=&E.wb[co*520];
    for (int ci=0;ci<32;ci++){
      uint4 wu=*(const uint4*)&wrow[ci*16];
      float w[9];
      w[0]=bflo(wu.x); w[1]=bfhi(wu.x); w[2]=bflo(wu.y); w[3]=bfhi(wu.y);
      w[4]=bflo(wu.z); w[5]=bfhi(wu.z); w[6]=bflo(wu.w); w[7]=bfhi(wu.w);
      w[8]=bfs(wrow[ci*16+8]);
      const float* hrow=&E.h0[ci*240+(2*oy)*16];
      #pragma unroll
      for (int ky=0;ky<3;ky++){
        float4 r0=*(const float4*)(hrow+ky*16+0);
        float4 r1=*(const float4*)(hrow+ky*16+4);
        float4 r2=*(const float4*)(hrow+ky*16+8);
        float4 r3=*(const float4*)(hrow+ky*16+12);
        float r[15]={r0.x,r0.y,r0.z,r0.w,r1.x,r1.y,r1.z,r1.w,r2.x,r2.y,r2.z,r2.w,r3.x,r3.y,r3.z};
        #pragma unroll
        for(int kx=0;kx<3;kx++){
          float wv=w[ky*3+kx];
          #pragma unroll
          for(int q=0;q<7;q++) acc[q]+=wv*r[2*q+kx];
        }
      }
    }
    #pragma unroll
    for(int q=0;q<7;q++) E.h1[co*49+oy*7+q]=fmaxf(acc[q],0.0f);
  }
  __syncthreads();
  // restage Wc2
  for (int i=tid;i<16384;i+=256){
    int tap=i&15, ci=(i>>4)&31, co=i>>9;
    E.wb[co*520+ci*16+tap] = (tap<9) ? f2bf(Wc2[co*288+ci*9+tap]) : (unsigned short)0;
  }
  __syncthreads();

  // conv2: 32->32, 7x7 -> 3x3, stride2, relu
  for (int i=tid;i<288;i+=256){
    int co=i/9, p=i%9, oy=p/3, ox=p%3;
    float acc=bc2[co];
    const unsigned short* wrow=&E.wb[co*520];
    for(int ci=0;ci<32;ci++){
      const float* hb=&E.h1[ci*49+2*oy*7+2*ox];
      uint4 wu=*(const uint4*)&wrow[ci*16];
      acc += bflo(wu.x)*hb[0]  + bfhi(wu.x)*hb[1]  + bflo(wu.y)*hb[2]
           + bfhi(wu.y)*hb[7]  + bflo(wu.z)*hb[8]  + bfhi(wu.z)*hb[9]
           + bflo(wu.w)*hb[14] + bfhi(wu.w)*hb[15] + bfs(wrow[ci*16+8])*hb[16];
    }
    E.feat[i]=fmaxf(acc,0.0f);
  }
  __syncthreads();

  // heads
  if (tid<64){
    const int j=tid>>3, kk=tid&7;
    float s1=0.f,s2=0.f;
    const float* wm=Wm+j*288;
    const float* wl=Wlv+j*288;
    #pragma unroll 6
    for(int m=kk*36;m<kk*36+36;m++){ float f=E.feat[m]; s1+=f*wm[m]; s2+=f*wl[m]; }
    #pragma unroll
    for(int d=4;d>0;d>>=1){ s1+=__shfl_down(s1,d,64); s2+=__shfl_down(s2,d,64); }
    if(kk==0){
      size_t o=(size_t)n*8+j;
      float am=s1+bm[j];
      float lv=sigm(s2+blv[j]);
      float av=am+eps[o]*__expf(0.5f*lv);
      out[OFF_AM+o]=am;
      out[OFF_ALV+o]=lv;
      out[OFF_A+o]=av;
    }
  }
}

// ===================== Main kernel: 32 seq blocks + 4096 decoder blocks =====================
struct DecSh {
  float aa[8];
  float d0[288];
  float t0[1680];                        // [ci][52] (+tail pad for OOB-safe reads)
  float t1[7200];                        // [co][225]
  alignas(16) unsigned short wb[16648];  // bf16: [co][ci][16] (T1, stride 520) then [tap][ci][32] (T2)
};
struct SeqSh {
  float a_loc[1024];
  float a0[8];
  float h[52];
  float gates[200];
  float wa[152];
  float logit[4];
  float alpha[384];
  float muf[512];
  float Sigf[2048];
  float Sigp[2048];
};
union MainSh { DecSh d; SeqSh q; };

#define FMA2(u, k) { float lo_=bflo(u), hi_=bfhi(u); \
  acc0[k]+=lo_*tA; acc1[k]+=lo_*tB; acc0[(k)+1]+=hi_*tA; acc1[(k)+1]+=hi_*tB; }

__global__ __launch_bounds__(512,2) void k_main(
    const float* __restrict__ Wd, const float* __restrict__ bd,
    const float* __restrict__ Wt0, const float* __restrict__ bt0,
    const float* __restrict__ Wt1, const float* __restrict__ bt1,
    const float* __restrict__ Wt2, const float* __restrict__ bt2,
    const float* __restrict__ Wg, const float* __restrict__ bgp,
    const float* __restrict__ Ag, const float* __restrict__ Bg, const float* __restrict__ Cg,
    const float* __restrict__ a_init,
    const float* __restrict__ W_ih, const float* __restrict__ W_hh,
    const float* __restrict__ b_ih, const float* __restrict__ b_hh,
    const float* __restrict__ Wa, const float* __restrict__ ba,
    float* __restrict__ out)
{
  __shared__ MainSh sh;
  const int tid=threadIdx.x;
  const float* aglob = out + OFF_A;

  if (blockIdx.x < 32){
    // ================= sequential path (one batch per block) =================
    SeqSh& Q = sh.q;
    const int b=blockIdx.x;
    for (int i=tid;i<1024;i+=512){ int s=i>>3, j=i&7; Q.a_loc[i]=aglob[((size_t)s*32+b)*8+j]; }
    if (tid<8)   Q.a0[tid]=a_init[tid];
    if (tid<150) Q.wa[tid]=Wa[tid];
    if (tid<50)  Q.h[tid]=0.f;
    float wr[50], wi[8], bsum=0.f, creg=0.f;
    if (tid<200){
      #pragma unroll
      for(int k=0;k<50;k++) wr[k]=W_hh[tid*50+k];
      #pragma unroll
      for(int j=0;j<8;j++) wi[j]=W_ih[tid*8+j];
      bsum=b_ih[tid]+b_hh[tid];
    }
    __syncthreads();
    for (int s=0;s<128;s++){
      if (tid<200){
        float aA=bsum, aB=0.f;
        const float* ap = (s==0) ? Q.a0 : (Q.a_loc + (s-1)*8);
        #pragma unroll
        for(int j=0;j<8;j++) aA+=ap[j]*wi[j];
        #pragma unroll
        for(int k=0;k<50;k+=2){ aA+=Q.h[k]*wr[k]; aB+=Q.h[k+1]*wr[k+1]; }
        Q.gates[tid]=aA+aB;
      } else if (tid>=208 && tid<211){
        if (s>0){
          int j=tid-208;
          float lv=ba[j];
          const float* wap=&Q.wa[j*50];
          #pragma unroll 5
          for(int k=0;k<50;k++) lv+=Q.h[k]*wap[k];
          Q.logit[j]=lv;
        }
      }
      __syncthreads();
      if (tid<50){
        float ig=sigm(Q.gates[tid]);
        float fg=sigm(Q.gates[50+tid]);
        float gg=tanhx(Q.gates[100+tid]);
        float og=sigm(Q.gates[150+tid]);
        creg=fg*creg+ig*gg;
        Q.h[tid]=og*tanhx(creg);
      } else if (tid>=64 && tid<67 && s>0){
        int j=tid-64;
        float l0=Q.logit[0], l1=Q.logit[1], l2=Q.logit[2];
        float mx=fmaxf(l0,fmaxf(l1,l2));
        float e0=__expf(l0-mx), e1=__expf(l1-mx), e2=__expf(l2-mx);
        float lj=(j==0)?l0:((j==1)?l1:l2);
        Q.alpha[(s-1)*3+j]=__expf(lj-mx)/(e0+e1+e2);
      }
      __syncthreads();
    }
    if (tid<3){
      float lv=ba[tid];
      const float* wap=&Q.wa[tid*50];
      #pragma unroll 5
      for(int k=0;k<50;k++) lv+=Q.h[k]*wap[k];
      Q.logit[tid]=lv;
    }
    __syncthreads();
    if (tid<3){
      float l0=Q.logit[0], l1=Q.logit[1], l2=Q.logit[2];
      float mx=fmaxf(l0,fmaxf(l1,l2));
      float e0=__expf(l0-mx), e1=__expf(l1-mx), e2=__expf(l2-mx);
      float lj=(tid==0)?l0:((tid==1)?l1:l2);
      Q.alpha[127*3+tid]=__expf(lj-mx)/(e0+e1+e2);
    }
    __syncthreads();
    if (tid>=64) return;

    // ---- Kalman filter (one wave; r=tid>>3, c=tid&7) ----
    const int r=tid>>3, c=tid&7;
    float A0=0,A1=0,A2=0,B0=0,B1=0,B2=0,C0=0,C1=0,C2=0;
    if (r<4&&c<4){ A0=Ag[r*4+c]; A1=Ag[16+r*4+c]; A2=Ag[32+r*4+c]; }
    if (r<4){ B0=Bg[r*8+c]; B1=Bg[32+r*8+c]; B2=Bg[64+r*8+c]; }
    if (c<4){ C0=Cg[r*4+c]; C1=Cg[32+r*4+c]; C2=Cg[64+r*4+c]; }
    float mu0=0,mu1=0,mu2=0,mu3=0, Sg=0.f;
    for (int s=0;s<128;s++){
      float al0=Q.alpha[s*3+0], al1=Q.alpha[s*3+1], al2=Q.alpha[s*3+2];
      float At=al0*A0+al1*A1+al2*A2;
      float Bt=al0*B0+al1*B1+al2*B2;
      float Ct=al0*C0+al1*C1+al2*C2;
      float mp0,mp1,mp2,mp3;
      {
        float mcc=(c==0)?mu0:((c==1)?mu1:((c==2)?mu2:((c==3)?mu3:0.f)));
        float vA=At*mcc;
        vA+=__shfl_xor(vA,1,64); vA+=__shfl_xor(vA,2,64);
        float uc;
        if (s==0) uc=Q.a0[c]; else uc=Q.a_loc[(s-1)*8+c];
        float vB=Bt*uc;
        vB+=__shfl_xor(vB,1,64); vB+=__shfl_xor(vB,2,64); vB+=__shfl_xor(vB,4,64);
        float comb=vA+vB;
        mp0=__shfl(comb,0,64); mp1=__shfl(comb,8,64); mp2=__shfl(comb,16,64); mp3=__shfl(comb,24,64);
      }
      float Sp;
      {
        float T=0.f;
        #pragma unroll
        for(int k=0;k<4;k++) T+=__shfl(At,(r<<3)|k,64)*__shfl(Sg,(k<<3)|c,64);
        float sp=0.f;
        #pragma unroll
        for(int k=0;k<4;k++) sp+=__shfl(T,(r<<3)|k,64)*__shfl(At,(c<<3)|k,64);
        Sp=sp+((r==c)?0.08f:0.f);
      }
      if (s==0){ mp0=0;mp1=0;mp2=0;mp3=0; Sp=(r==c)?20.f:0.f; }
      if (r<4&&c<4) Q.Sigp[s*16+r*4+c]=Sp;
      float rr;
      {
        float mpc=(c==0)?mp0:((c==1)?mp1:((c==2)?mp2:((c==3)?mp3:0.f)));
        float v=Ct*mpc;
        v+=__shfl_xor(v,1,64); v+=__shfl_xor(v,2,64);
        rr=Q.a_loc[s*8+r]-v;
      }
      float CP=0.f;
      #pragma unroll
      for(int k=0;k<4;k++) CP+=__shfl(Ct,(r<<3)|k,64)*__shfl(Sp,(k<<3)|c,64);
      float Sm=0.f;
      #pragma unroll
      for(int k=0;k<4;k++) Sm+=__shfl(CP,(r<<3)|k,64)*__shfl(Ct,(c<<3)|k,64);
      Sm+=(r==c)?0.03f:0.f;
      float gA=Sm, gB=(r==c)?1.f:0.f;
      #pragma unroll
      for(int k=0;k<8;k++){
        float piv=__shfl(gA,(k<<3)|k,64);
        float pinv=1.f/piv;
        float sa=__shfl(gA,(k<<3)|c,64)*pinv;
        float sb=__shfl(gB,(k<<3)|c,64)*pinv;
        float fac=__shfl(gA,(r<<3)|k,64);
        bool dg=(r==k);
        gA=dg?sa:fmaf(-fac,sa,gA);
        gB=dg?sb:fmaf(-fac,sb,gB);
      }
      float Kt=0.f;
      #pragma unroll
      for(int k=0;k<8;k++) Kt+=__shfl(CP,(k<<3)|r,64)*__shfl(gB,(k<<3)|c,64);
      float resc=__shfl(rr,c<<3,64);
      float vv=Kt*resc;
      vv+=__shfl_xor(vv,1,64); vv+=__shfl_xor(vv,2,64); vv+=__shfl_xor(vv,4,64);
      float mufr=((r==0)?mp0:((r==1)?mp1:((r==2)?mp2:mp3)))+vv;
      float nm0=__shfl(mufr,0,64), nm1=__shfl(mufr,8,64), nm2=__shfl(mufr,16,64), nm3=__shfl(mufr,24,64);
      if (r<4&&c==0) Q.muf[s*4+r]=mufr;
      float IK=(r==c)?1.f:0.f;
      #pragma unroll
      for(int m=0;m<8;m++) IK-=__shfl(Kt,(r<<3)|m,64)*__shfl(Ct,(m<<3)|c,64);
      float T2=0.f;
      #pragma unroll
      for(int k=0;k<4;k++) T2+=__shfl(IK,(r<<3)|k,64)*__shfl(Sp,(k<<3)|c,64);
      float Sf=0.f;
      #pragma unroll
      for(int k=0;k<4;k++) Sf+=__shfl(T2,(r<<3)|k,64)*__shfl(IK,(c<<3)|k,64);
      float kk2=0.f;
      #pragma unroll
      for(int m=0;m<8;m++) kk2+=__shfl(Kt,(r<<3)|m,64)*__shfl(Kt,(c<<3)|m,64);
      Sf+=0.03f*kk2;
      if (r<4&&c<4) Q.Sigf[s*16+r*4+c]=Sf;
      mu0=nm0; mu1=nm1; mu2=nm2; mu3=nm3; Sg=Sf;
    }
    if (r<4&&c==0) out[OFF_MU+((size_t)127*32+b)*4+r]=Q.muf[127*4+r];
    if (r<4&&c<4)  out[OFF_SG+((size_t)127*32+b)*16+r*4+c]=Q.Sigf[127*16+r*4+c];
    float ms0=Q.muf[508], ms1=Q.muf[509], ms2=Q.muf[510], ms3=Q.muf[511];
    float Ss=(r<4&&c<4)?Q.Sigf[127*16+r*4+c]:0.f;
    for (int n2=126;n2>=0;n2--){
      float al0=Q.alpha[(n2+1)*3+0], al1=Q.alpha[(n2+1)*3+1], al2=Q.alpha[(n2+1)*3+2];
      float An=al0*A0+al1*A1+al2*A2;
      float Sfv=(r<4&&c<4)?Q.Sigf[n2*16+r*4+c]:0.f;
      float Spn=(r<4&&c<4)?Q.Sigp[(n2+1)*16+r*4+c]:0.f;
      float gA=Spn, gB=(r==c)?1.f:0.f;
      #pragma unroll
      for(int k=0;k<4;k++){
        float piv=__shfl(gA,(k<<3)|k,64);
        float pinv=1.f/piv;
        float sa=__shfl(gA,(k<<3)|c,64)*pinv;
        float sb=__shfl(gB,(k<<3)|c,64)*pinv;
        float fac=__shfl(gA,(r<<3)|k,64);
        bool dg=(r==k);
        gA=dg?sa:fmaf(-fac,sa,gA);
        gB=dg?sb:fmaf(-fac,sb,gB);
      }
      float T=0.f;
      #pragma unroll
      for(int k=0;k<4;k++) T+=__shfl(Sfv,(r<<3)|k,64)*__shfl(An,(c<<3)|k,64);
      float J=0.f;
      #pragma unroll
      for(int k=0;k<4;k++) J+=__shfl(T,(r<<3)|k,64)*__shfl(gB,(k<<3)|c,64);
      float dmc;
      {
        float msc=(c==0)?ms0:((c==1)?ms1:((c==2)?ms2:((c==3)?ms3:0.f)));
        float mfn=Q.muf[(n2+1)*4+((c<4)?c:0)];
        dmc=(c<4)?(msc-mfn):0.f;
      }
      float v=J*dmc;
      v+=__shfl_xor(v,1,64); v+=__shfl_xor(v,2,64);
      float munr=Q.muf[n2*4+((r<4)?r:0)]+v;
      float Dv=Ss-Spn;
      float T2=0.f;
      #pragma unroll
      for(int k=0;k<4;k++) T2+=__shfl(J,(r<<3)|k,64)*__shfl(Dv,(k<<3)|c,64);
      float Sn=Sfv;
      #pragma unroll
      for(int k=0;k<4;k++) Sn+=__shfl(T2,(r<<3)|k,64)*__shfl(J,(c<<3)|k,64);
      if (r<4&&c==0) out[OFF_MU+((size_t)n2*32+b)*4+r]=munr;
      if (r<4&&c<4)  out[OFF_SG+((size_t)n2*32+b)*16+r*4+c]=Sn;
      ms0=__shfl(munr,0,64); ms1=__shfl(munr,8,64); ms2=__shfl(munr,16,64); ms3=__shfl(munr,24,64);
      Ss=Sn;
    }
    return;
  }

  // ================= decoder path (one image per block) =================
  DecSh& D = sh.d;
  const int n = blockIdx.x - 32;
  if (tid<8) D.aa[tid]=aglob[(size_t)n*8+tid];
  __syncthreads();
  // d0 + stage Wt1 bf16 [co][ci][16] (stride 520) + init t1 = bias
  if (tid<288){
    float acc=bd[tid];
    #pragma unroll
    for(int j=0;j<8;j++) acc+=D.aa[j]*Wd[tid*8+j];
    D.d0[tid]=acc;
  }
  for (int i=tid;i<16384;i+=512){
    int tap=i&15, ci=(i>>4)&31, co=i>>9;
    D.wb[co*520+ci*16+tap] = (tap<9) ? f2bf(Wt1[ci*288+co*9+tap]) : (unsigned short)0;
  }
  for (int i=tid;i<7200;i+=512) D.t1[i]=bt1[i/225];
  __syncthreads();
  // convT0 gather: 3x3 -> 7x7, relu
  for (int i=tid;i<1568;i+=512){
    int co=i/49, p=i%49, oh=p/7, ow=p%7;
    float acc=bt0[co];
    #pragma unroll
    for(int kh=0;kh<3;kh++){
      int iht=oh-kh;
      if (iht<0 || (iht&1) || iht>4) continue;
      int ih=iht>>1;
      #pragma unroll
      for(int kw=0;kw<3;kw++){
        int iwt=ow-kw;
        if (iwt<0 || (iwt&1) || iwt>4) continue;
        int iw=iwt>>1;
        const float* wp=Wt0+co*9+kh*3+kw;
        const float* dp=&D.d0[ih*3+iw];
        for(int ci=0;ci<32;ci++) acc+=dp[ci*9]*wp[ci*288];
      }
    }
    D.t0[co*52+p]=fmaxf(acc,0.0f);
  }
  __syncthreads();
  // convT1: per-thread 9-tap register accumulators (t0 read ONCE per ci), then 9 scatter phases
  {
    const int co=tid>>4, p0=(tid&15)*4;
    float accT[36];
    #pragma unroll
    for(int t=0;t<36;t++) accT[t]=0.f;
    const unsigned short* wrow=&D.wb[co*520];
    for (int ci=0;ci<32;ci++){
      float4 tv=*(const float4*)&D.t0[ci*52+p0];
      uint4 wu=*(const uint4*)&wrow[ci*16];
      float wv[9];
      wv[0]=bflo(wu.x); wv[1]=bfhi(wu.x); wv[2]=bflo(wu.y); wv[3]=bfhi(wu.y);
      wv[4]=bflo(wu.z); wv[5]=bfhi(wu.z); wv[6]=bflo(wu.w); wv[7]=bfhi(wu.w);
      wv[8]=bfs(wrow[ci*16+8]);
      #pragma unroll
      for(int tap=0;tap<9;tap++){
        accT[tap*4+0]+=wv[tap]*tv.x;
        accT[tap*4+1]+=wv[tap]*tv.y;
        accT[tap*4+2]+=wv[tap]*tv.z;
        accT[tap*4+3]+=wv[tap]*tv.w;
      }
    }
    for (int tap=0;tap<9;tap++){
      const int kh=tap/3, kw=tap%3;
      #pragma unroll
      for(int q=0;q<4;q++){
        int p=p0+q;
        if (p<49){
          int ih=p/7, iw=p%7;
          D.t1[co*225+(2*ih+kh)*15+(2*iw+kw)]+=accT[tap*4+q];
        }
      }
      __syncthreads();
    }
  }
  // relu(t1); restage Wt2 bf16 [tap][ci][co]
  for (int i=tid;i<7200;i+=512) D.t1[i]=fmaxf(D.t1[i],0.0f);
  for (int i=tid;i<9216;i+=512){
    int tap=i>>10, ci=(i>>5)&31, co=i&31;
    D.wb[i]=f2bf(Wt2[ci*288+co*9+tap]);
  }
  __syncthreads();
  // convT2 fused with relu + <Wg> reduction + sigmoid (parity-class gather, 2 px x 32 co per thread)
  {
    const int cls=tid>>7, ph=cls>>1, pw=cls&1;
    const int l=tid&127, ii=l>>3, j0=l&7;
    float acc0[32], acc1[32];
    #pragma unroll
    for(int co=0;co<32;co++){ float bz=bt2[co]; acc0[co]=bz; acc1[co]=bz; }
    const int nth=ph?1:2, ntw=pw?1:2;
    for (int th=0;th<nth;th++){
      const int kh=ph?1:(2*th);
      const int ih=ii-th;
      const bool vh=(ih>=0)&&(ih<15);
      for (int tw=0;tw<ntw;tw++){
        const int kw=pw?1:(2*tw);
        const int iwA=j0-tw, iwB=j0+8-tw;
        const bool vA=vh&&(iwA>=0);
        const bool vB=vh&&(iwB<15);
        const int tap=kh*3+kw;
        const int bA=(vh?ih:0)*15+(vA?iwA:0);
        const int bB=(vh?ih:0)*15+(vB?iwB:0);
        const unsigned short* wt=&D.wb[tap*1024];
        for (int ci=0;ci<32;ci++){
          float tA=D.t1[ci*225+bA]; if(!vA) tA=0.f;
          float tB=D.t1[ci*225+bB]; if(!vB) tB=0.f;
          const uint4* wp4=(const uint4*)&wt[ci*32];
          uint4 u=wp4[0];
          FMA2(u.x,0)  FMA2(u.y,2)  FMA2(u.z,4)  FMA2(u.w,6)
          u=wp4[1];
          FMA2(u.x,8)  FMA2(u.y,10) FMA2(u.z,12) FMA2(u.w,14)
          u=wp4[2];
          FMA2(u.x,16) FMA2(u.y,18) FMA2(u.z,20) FMA2(u.w,22)
          u=wp4[3];
          FMA2(u.x,24) FMA2(u.y,26) FMA2(u.z,28) FMA2(u.w,30)
        }
      }
    }
    float s0=bgp[0], s1=bgp[0];
    #pragma unroll
    for(int co=0;co<32;co++){ s0+=fmaxf(acc0[co],0.f)*Wg[co]; s1+=fmaxf(acc1[co],0.f)*Wg[co]; }
    const int oh=ph+2*ii;
    size_t ob=(size_t)n*1024+(size_t)oh*32;
    out[ob+pw+2*j0]=sigm(s0);
    out[ob+pw+2*(j0+8)]=sigm(s1);
  }
}

extern "C" void kernel_launch(void* const* d_in, const int* in_sizes, int n_in,
                              void* d_out, int out_size, void* d_ws, size_t ws_size,
                              hipStream_t stream)
{
  const float* x    =(const float*)d_in[0];
  const float* eps  =(const float*)d_in[1];
  const float* Wc0  =(const float*)d_in[2];
  const float* bc0  =(const float*)d_in[3];
  const float* Wc1  =(const float*)d_in[4];
  const float* bc1  =(const float*)d_in[5];
  const float* Wc2  =(const float*)d_in[6];
  const float* bc2  =(const float*)d_in[7];
  const float* Wm   =(const float*)d_in[8];
  const float* bm   =(const float*)d_in[9];
  const float* Wlv  =(const float*)d_in[10];
  const float* blv  =(const float*)d_in[11];
  const float* Wd   =(const float*)d_in[12];
  const float* bd   =(const float*)d_in[13];
  const float* Wt0  =(const float*)d_in[14];
  const float* bt0  =(const float*)d_in[15];
  const float* Wt1  =(const float*)d_in[16];
  const float* bt1  =(const float*)d_in[17];
  const float* Wt2  =(const float*)d_in[18];
  const float* bt2  =(const float*)d_in[19];
  const float* Wg   =(const float*)d_in[20];
  const float* bg   =(const float*)d_in[21];
  const float* A    =(const float*)d_in[22];
  const float* Bm   =(const float*)d_in[23];
  const float* Cm   =(const float*)d_in[24];
  const float* a0   =(const float*)d_in[25];
  const float* W_ih =(const float*)d_in[26];
  const float* W_hh =(const float*)d_in[27];
  const float* b_ih =(const float*)d_in[28];
  const float* b_hh =(const float*)d_in[29];
  const float* Wa   =(const float*)d_in[30];
  const float* ba   =(const float*)d_in[31];
  float* out=(float*)d_out;

  k_enc<<<4096,256,0,stream>>>(x,eps,Wc0,bc0,Wc1,bc1,Wc2,bc2,Wm,bm,Wlv,blv,out);
  k_main<<<4128,512,0,stream>>>(Wd,bd,Wt0,bt0,Wt1,bt1,Wt2,bt2,Wg,bg,A,Bm,Cm,a0,
                                W_ih,W_hh,b_ih,b_hh,Wa,ba,out);
}